// Round 5
// baseline (947.766 us; speedup 1.0000x reference)
//
#include <hip/hip_runtime.h>

// ============================================================================
// CrossAttention fused pipeline, MI355X gfx950.  Round 10.
// - R10 single lever: tail GEMMs (O-proj, fc1, fc2, final) ported to the
//   learn_hip-verified 8-phase schedule (T3+T4+T5): BM=256 BN=128 BK=64,
//   8 waves, 3-buffer LDS (144KB, depth-2 prefetch), boundary vmcnt(6)
//   (never 0 in main loop), 2 big phases per K-tile {ds_read 12x b128 ||
//   stage half-tile || barrier -> lgkm(0) -> setprio(1) 16 MFMA}, template
//   barrier placement.  Grid 256 blocks = 1/CU exact.  This is the ONLY
//   structure that broke the 2-phase ~36% ceiling in learn_hip (m196-m201);
//   all 2-phase variants (R6/R8/R9 here, m131/m139 there) conserve stall.
// - Kept: QKV 4-wave BK=32 gemm (20 waves/CU), attn R9 (8x16 rows, counted
//   vmcnt, setprio, XCD swizzle), vec4 packs, XCD swizzles everywhere.
// ============================================================================

typedef unsigned short u16;
typedef __attribute__((ext_vector_type(8))) short  bf16x8;
typedef __attribute__((ext_vector_type(4))) short  s16x4;
typedef __attribute__((ext_vector_type(4))) float  f32x4;

#define GLL16(gp, lp) __builtin_amdgcn_global_load_lds(                     \
    (__attribute__((address_space(1))) const void*)(gp),                    \
    (__attribute__((address_space(3))) void*)(lp), 16, 0, 0)

__device__ __forceinline__ u16 f2bf(float x) {
  union { float f; unsigned u; } v; v.f = x;
  return (u16)((v.u + 0x7FFF + ((v.u >> 16) & 1)) >> 16);   // RNE
}
__device__ __forceinline__ float bf2f(u16 h) {
  union { unsigned u; float f; } v; v.u = ((unsigned)h) << 16;
  return v.f;
}
__device__ __forceinline__ f32x4 zero4() { f32x4 z = {0.f, 0.f, 0.f, 0.f}; return z; }

// ---------------------------------------------------------------------------
// Packing: activations (base,fusion) and 7 weights, fp32 -> bf16, x4 vector.
// ---------------------------------------------------------------------------
__global__ __launch_bounds__(256) void pack_act(const float* __restrict__ a,
                                                const float* __restrict__ b,
                                                u16* __restrict__ outa,
                                                u16* __restrict__ outb) {
  size_t i = (size_t)blockIdx.x * 256 + threadIdx.x;        // vec4 index
  const f32x4* in = (const f32x4*)(blockIdx.y ? b : a);
  s16x4* out = (s16x4*)(blockIdx.y ? outb : outa);
  f32x4 v = in[i];
  s16x4 o;
  o[0] = (short)f2bf(v[0]); o[1] = (short)f2bf(v[1]);
  o[2] = (short)f2bf(v[2]); o[3] = (short)f2bf(v[3]);
  out[i] = o;
}

__global__ __launch_bounds__(256) void pack_w(
    const float* __restrict__ w0, const float* __restrict__ w1,
    const float* __restrict__ w2, const float* __restrict__ w3,
    const float* __restrict__ w4, const float* __restrict__ w5,
    const float* __restrict__ w6, u16* __restrict__ out) {
  size_t i = (size_t)blockIdx.x * 256 + threadIdx.x;        // vec4 index
  const float* in;
  switch (blockIdx.y) {
    case 0: in = w0; break;  case 1: in = w1; break;
    case 2: in = w2; break;  case 3: in = w3; break;
    case 4: in = w4; break;  case 5: in = w5; break;
    default: in = w6; break;
  }
  f32x4 v = ((const f32x4*)in)[i];
  s16x4 o;
  o[0] = (short)f2bf(v[0]); o[1] = (short)f2bf(v[1]);
  o[2] = (short)f2bf(v[2]); o[3] = (short)f2bf(v[3]);
  ((s16x4*)(out + (size_t)blockIdx.y * 1048576))[i] = o;
}

// ---------------------------------------------------------------------------
// GEMM (4-wave, QKV only): C[M,N] = A[M,K] @ W[N,K]^T, bf16, BK=32, dbuf LDS.
// ---------------------------------------------------------------------------
#define EPI_QKV       0
#define EPI_BF16      1
#define EPI_SILU_BF16 4
#define EPI_BIAS_F32  6

template <int EPI>
__global__ __launch_bounds__(256) void gemm_bt(
    const u16* __restrict__ A, int lda,
    const u16* __restrict__ W, int ldw,
    int M, int N, int K,
    float* __restrict__ outF, u16* __restrict__ outU,
    const float* __restrict__ bias,
    const u16* __restrict__ A2) {
  __shared__ u16 As[2][128 * 32];   // 2 x 8 KB
  __shared__ u16 Bs[2][128 * 32];   // 2 x 8 KB
  int tid = threadIdx.x;
  int l = tid & 63, w = tid >> 6;
  int wr = w >> 1, wc = w & 1, lr = l & 15, lq = l >> 4;

  int fid = blockIdx.y * 8 + blockIdx.x;
  int swz = (fid & 7) * 64 + (fid >> 3);
  int m0 = (swz >> 3) * 128, n0 = (swz & 7) * 128;

  const u16* Ap = A;
  const u16* Wp = W;
  u16* outUp = outU;
  if constexpr (EPI == EPI_QKV) {
    int z = blockIdx.z;
    if (z) Ap = A2;                      // K,V read fusion
    Wp = W + (size_t)z * 1048576;        // wq / wk / wv
    outUp = outU + (size_t)z * 8388608;  // Q2 / K2 / Vt
  }

  f32x4 acc[4][4];
#pragma unroll
  for (int i = 0; i < 4; i++)
#pragma unroll
    for (int j = 0; j < 4; j++) acc[i][j] = zero4();

  auto stage = [&](const u16* src, int ld, int r0, int k0, u16* lds) {
#pragma unroll
    for (int j = 0; j < 2; ++j) {
      int seg = j * 256 + tid;               // 512 segs x 16B
      int row = seg >> 2, sp = seg & 3;
      const u16* g = src + (size_t)(r0 + row) * ld + k0 +
                     ((sp ^ ((row >> 1) & 3)) << 3);
      GLL16(g, lds + seg * 8);               // lane-contiguous LDS dest
    }
  };

  int nk = K >> 5;
  stage(Ap, lda, m0, 0, As[0]);
  stage(Wp, ldw, n0, 0, Bs[0]);
  for (int kt = 0; kt < nk; ++kt) {
    __syncthreads();
    if (kt + 1 < nk) {
      stage(Ap, lda, m0, (kt + 1) << 5, As[(kt + 1) & 1]);
      stage(Wp, ldw, n0, (kt + 1) << 5, Bs[(kt + 1) & 1]);
    }
    const u16* Ab = As[kt & 1];
    const u16* Bb = Bs[kt & 1];
    bf16x8 af[4], bw[4];
    int slot = (lq ^ ((lr >> 1) & 3)) << 3;
#pragma unroll
    for (int mi = 0; mi < 4; mi++)
      af[mi] = *(const bf16x8*)&Ab[(wr * 64 + mi * 16 + lr) * 32 + slot];
#pragma unroll
    for (int ni = 0; ni < 4; ni++)
      bw[ni] = *(const bf16x8*)&Bb[(wc * 64 + ni * 16 + lr) * 32 + slot];
#pragma unroll
    for (int mi = 0; mi < 4; mi++)
#pragma unroll
      for (int ni = 0; ni < 4; ni++)
        acc[mi][ni] = __builtin_amdgcn_mfma_f32_16x16x32_bf16(af[mi], bw[ni],
                                                              acc[mi][ni], 0, 0, 0);
  }

#pragma unroll
  for (int mi = 0; mi < 4; mi++) {
#pragma unroll
    for (int ni = 0; ni < 4; ni++) {
      int col = n0 + wc * 64 + ni * 16 + lr;
#pragma unroll
      for (int r = 0; r < 4; r++) {
        int row = m0 + wr * 64 + mi * 16 + lq * 4 + r;
        float v = acc[mi][ni][r];
        if constexpr (EPI == EPI_QKV) {
          int b = row >> 10, t = row & 1023, h = col >> 6, d = col & 63;
          int z = blockIdx.z;
          if (z == 0) {                       // Q2: [bh][t][64] plain
            outUp[((size_t)(b * 16 + h) * 1024 + t) * 64 + d] = f2bf(v);
          } else if (z == 1) {                // K2: XOR-(t&7) swizzled rows
            size_t base = ((size_t)(b * 16 + h) * 1024 + t) * 64;
            outUp[base + (((d >> 3) ^ (t & 7)) << 3) + (d & 7)] = f2bf(v);
          } else {                            // Vt: [bh][d][t], XOR-(d&7) per 64-chunk
            size_t o = ((size_t)(b * 16 + h) * 64 + d) * 1024 + (t & ~63) +
                       ((((t >> 3) & 7) ^ (d & 7)) << 3) + (t & 7);
            outUp[o] = f2bf(v);
          }
        } else if constexpr (EPI == EPI_BF16) {
          outUp[(size_t)row * N + col] = f2bf(v);
        } else if constexpr (EPI == EPI_SILU_BF16) {
          float z = v + bias[col];
          outUp[(size_t)row * N + col] = f2bf(z / (1.f + __expf(-z)));
        } else {
          outF[(size_t)row * N + col] = v + bias[col];
        }
      }
    }
  }
}

// ---------------------------------------------------------------------------
// GEMM 8-phase (tail GEMMs): BM=256 BN=128 BK=64, 8 waves (2x4), 3-buf LDS.
// M=8192, K=1024, lda=ldw=1024 hardcoded.  Grid (8, 32) = 256 blocks = 1/CU.
// Schedule per K-tile kt (T3+T4+T5, m201 template adapted):
//   boundary: vmcnt(6) [last iter: 0] + barrier   (buf[kt] staged, all waves)
//   P0: ds_read af[0..3][kk0,1] + bw[0..1][kk0,1] (12 b128); stage half0(kt+2)
//       barrier; lgkm(0); sched_barrier; setprio(1); 16 MFMA (mi0-3); setprio(0); barrier
//   P1: ds_read ag[0..3][kk0,1] (8 b128); stage half1(kt+2)
//       barrier; lgkm(0); sched_barrier; setprio(1); 16 MFMA (mi4-7); setprio(0)
// vmcnt math: 3 GLL/half-tile, 2 half/tile, depth-2 -> newest 6 = tile kt+1.
// LDS row = 64 bf16 = 128B = 8 slots; slot sp stored from src col (sp^(row&7)).
// ---------------------------------------------------------------------------
template <int EPI>
__global__ __launch_bounds__(512) void gemm8ph(
    const u16* __restrict__ A, const u16* __restrict__ W,
    int N, float* __restrict__ outF, u16* __restrict__ outU,
    const float* __restrict__ bias) {
  __shared__ u16 As[3][256 * 64];   // 3 x 32 KB
  __shared__ u16 Bs[3][128 * 64];   // 3 x 16 KB  (total 144 KB)
  int tid = threadIdx.x;
  int l = tid & 63, w = tid >> 6;                  // 8 waves
  int wr = w >> 2, wc = w & 3, lr = l & 15, lq = l >> 4;

  int fid = blockIdx.y * 8 + blockIdx.x;           // grid (8, 32)
  int swz = (fid & 7) * 32 + (fid >> 3);           // XCD-chunked, 256%8==0
  int m0 = (swz >> 3) * 256, n0 = (swz & 7) * 128;

  f32x4 acc[8][2];
#pragma unroll
  for (int i = 0; i < 8; i++)
#pragma unroll
    for (int j = 0; j < 2; j++) acc[i][j] = zero4();

  auto stageA = [&](int kt, int h, u16* lds) {     // 128 rows = 16 KB, 2 GLL
#pragma unroll
    for (int j = 0; j < 2; ++j) {
      int seg = j * 512 + tid;
      int row = seg >> 3, sp = seg & 7;
      const u16* g = A + (size_t)(m0 + h * 128 + row) * 1024 + (kt << 6) +
                     ((sp ^ (row & 7)) << 3);
      GLL16(g, lds + h * 8192 + seg * 8);
    }
  };
  auto stageB = [&](int kt, int h, u16* lds) {     // 64 rows = 8 KB, 1 GLL
    int seg = tid;
    int row = seg >> 3, sp = seg & 7;
    const u16* g = W + (size_t)(n0 + h * 64 + row) * 1024 + (kt << 6) +
                   ((sp ^ (row & 7)) << 3);
    GLL16(g, lds + h * 4096 + seg * 8);
  };

  // prologue: tiles 0 and 1, FIFO order (A0h0,B0h0,A0h1,B0h1, A1h0,...)
  stageA(0, 0, As[0]); stageB(0, 0, Bs[0]);
  stageA(0, 1, As[0]); stageB(0, 1, Bs[0]);
  stageA(1, 0, As[1]); stageB(1, 0, Bs[1]);
  stageA(1, 1, As[1]); stageB(1, 1, Bs[1]);

  for (int kt = 0; kt < 16; ++kt) {
    const u16* Ab = As[kt % 3];
    const u16* Bb = Bs[kt % 3];
    // ---- K-tile boundary: buf[kt] ready for ALL waves ----
    if (kt == 15) {
      asm volatile("s_waitcnt vmcnt(0)" ::: "memory");
    } else {
      asm volatile("s_waitcnt vmcnt(6)" ::: "memory");
    }
    __builtin_amdgcn_s_barrier();

    // ---- P0: mi 0..3, both kk ----
    bf16x8 af[4][2], bw[2][2];
#pragma unroll
    for (int kk = 0; kk < 2; kk++) {
#pragma unroll
      for (int mi = 0; mi < 4; mi++) {
        int r = wr * 128 + mi * 16 + lr;
        af[mi][kk] = *(const bf16x8*)&Ab[r * 64 + (((kk * 4 + lq) ^ (r & 7)) << 3)];
      }
#pragma unroll
      for (int ni = 0; ni < 2; ni++) {
        int r = wc * 32 + ni * 16 + lr;
        bw[ni][kk] = *(const bf16x8*)&Bb[r * 64 + (((kk * 4 + lq) ^ (r & 7)) << 3)];
      }
    }
    if (kt + 2 < 16) {
      stageA(kt + 2, 0, As[(kt + 2) % 3]);
      stageB(kt + 2, 0, Bs[(kt + 2) % 3]);
    }
    __builtin_amdgcn_s_barrier();
    asm volatile("s_waitcnt lgkmcnt(0)" ::: "memory");
    __builtin_amdgcn_sched_barrier(0);
    __builtin_amdgcn_s_setprio(1);
#pragma unroll
    for (int kk = 0; kk < 2; kk++)
#pragma unroll
      for (int mi = 0; mi < 4; mi++)
#pragma unroll
        for (int ni = 0; ni < 2; ni++)
          acc[mi][ni] = __builtin_amdgcn_mfma_f32_16x16x32_bf16(
              af[mi][kk], bw[ni][kk], acc[mi][ni], 0, 0, 0);
    __builtin_amdgcn_s_setprio(0);
    __builtin_amdgcn_s_barrier();

    // ---- P1: mi 4..7, both kk (bw reused from regs) ----
    bf16x8 ag[4][2];
#pragma unroll
    for (int kk = 0; kk < 2; kk++)
#pragma unroll
      for (int mi = 0; mi < 4; mi++) {
        int r = wr * 128 + (mi + 4) * 16 + lr;
        ag[mi][kk] = *(const bf16x8*)&Ab[r * 64 + (((kk * 4 + lq) ^ (r & 7)) << 3)];
      }
    if (kt + 2 < 16) {
      stageA(kt + 2, 1, As[(kt + 2) % 3]);
      stageB(kt + 2, 1, Bs[(kt + 2) % 3]);
    }
    __builtin_amdgcn_s_barrier();
    asm volatile("s_waitcnt lgkmcnt(0)" ::: "memory");
    __builtin_amdgcn_sched_barrier(0);
    __builtin_amdgcn_s_setprio(1);
#pragma unroll
    for (int kk = 0; kk < 2; kk++)
#pragma unroll
      for (int mi = 0; mi < 4; mi++)
#pragma unroll
        for (int ni = 0; ni < 2; ni++)
          acc[mi + 4][ni] = __builtin_amdgcn_mfma_f32_16x16x32_bf16(
              ag[mi][kk], bw[ni][kk], acc[mi + 4][ni], 0, 0, 0);
    __builtin_amdgcn_s_setprio(0);
    // P1-end barrier is the next iteration's boundary barrier; this iter's
    // ds_reads are lgkm-drained above, so stage(kt+3) overwrite is safe.
  }

#pragma unroll
  for (int mi = 0; mi < 8; mi++) {
#pragma unroll
    for (int ni = 0; ni < 2; ni++) {
      int col = n0 + wc * 32 + ni * 16 + lr;
#pragma unroll
      for (int r = 0; r < 4; r++) {
        int row = m0 + wr * 128 + mi * 16 + lq * 4 + r;
        float v = acc[mi][ni][r];
        if constexpr (EPI == EPI_BF16) {
          outU[(size_t)row * N + col] = f2bf(v);
        } else if constexpr (EPI == EPI_SILU_BF16) {
          float z = v + bias[col];
          outU[(size_t)row * N + col] = f2bf(z / (1.f + __expf(-z)));
        } else {
          outF[(size_t)row * N + col] = v + bias[col];
        }
      }
    }
  }
}

// ---------------------------------------------------------------------------
// Attention: two-pass recompute, 8 waves x 16 q-rows (512 thr), dbuf K/V.
// Grid (1024): qi = bid>>7, bh = (bid&7)*16 + ((bid>>3)&15)  (XCD-resident).
// ---------------------------------------------------------------------------
__global__ __launch_bounds__(512) void attn_kernel(
    const u16* __restrict__ Q2, const u16* __restrict__ K2,
    const u16* __restrict__ Vt, const float* __restrict__ alphap,
    float* __restrict__ masked_out, u16* __restrict__ attn_out) {
  __shared__ __align__(16) u16 Ks[2][4096];        // 16 KB
  __shared__ __align__(16) u16 Vs[2][4096];        // 16 KB
  __shared__ __align__(16) u16 Ps[8][16 * 72];     // 18 KB

  int tid = threadIdx.x;
  int l = tid & 63, w = tid >> 6, lr = l & 15, lq = l >> 4;   // w in 0..7

  int bid = blockIdx.x;
  int qi  = bid >> 7;
  int bh  = (bid & 7) * 16 + ((bid >> 3) & 15);
  int h = bh & 15, b = bh >> 4;
  int q0 = qi * 128;

  const u16* Qb = Q2 + (size_t)bh * 1024 * 64;
  const u16* Kb = K2 + (size_t)bh * 1024 * 64;
  const u16* Vb = Vt + (size_t)bh * 64 * 1024;
  float alpha = alphap[0];
  int qw = q0 + w * 16;

  auto stageK = [&](int kc, u16* dst) {
    int seg = tid;
    GLL16(Kb + (size_t)kc * 4096 + seg * 8, dst + seg * 8);
  };
  auto stageV = [&](int kc, u16* dst) {
    int seg = tid;
    GLL16(Vb + (size_t)(seg >> 3) * 1024 + kc * 64 + (seg & 7) * 8, dst + seg * 8);
  };

  bf16x8 qf[2];
#pragma unroll
  for (int kt = 0; kt < 2; kt++)
    qf[kt] = *(const bf16x8*)(Qb + (size_t)(qw + lr) * 64 + kt * 32 + lq * 8);

  float s1[4] = {0.f, 0.f, 0.f, 0.f};

  // ---- pass 1 ----
  stageK(0, Ks[0]);
  for (int kc = 0; kc < 16; ++kc) {
    __syncthreads();
    if (kc + 1 < 16) stageK(kc + 1, Ks[(kc + 1) & 1]);
    const u16* Kc = Ks[kc & 1];
    f32x4 acc[4];
#pragma unroll
    for (int ni = 0; ni < 4; ni++) acc[ni] = zero4();
    __builtin_amdgcn_s_setprio(1);
#pragma unroll
    for (int ni = 0; ni < 4; ++ni) {
      int t = ni * 16 + lr;
      bf16x8 k0 = *(const bf16x8*)&Kc[t * 64 + (((0 + lq) ^ (lr & 7)) << 3)];
      bf16x8 k1 = *(const bf16x8*)&Kc[t * 64 + (((4 + lq) ^ (lr & 7)) << 3)];
      acc[ni] = __builtin_amdgcn_mfma_f32_16x16x32_bf16(qf[0], k0, acc[ni], 0, 0, 0);
      acc[ni] = __builtin_amdgcn_mfma_f32_16x16x32_bf16(qf[1], k1, acc[ni], 0, 0, 0);
    }
    __builtin_amdgcn_s_setprio(0);
#pragma unroll
    for (int ni = 0; ni < 4; ni++)
#pragma unroll
      for (int r = 0; r < 4; r++)
        s1[r] += __expf(acc[ni][r] * 0.125f);
  }
#pragma unroll
  for (int r = 0; r < 4; r++) {
    float v = s1[r];
    v += __shfl_xor(v, 1); v += __shfl_xor(v, 2);
    v += __shfl_xor(v, 4); v += __shfl_xor(v, 8);
    s1[r] = 1.0f / v;
  }

  // ---- pass 2 ----
  float s2[4] = {0.f, 0.f, 0.f, 0.f};
  f32x4 oacc[4];
#pragma unroll
  for (int dg = 0; dg < 4; dg++) oacc[dg] = zero4();

  stageK(0, Ks[0]);
  stageV(0, Vs[0]);
  for (int kc = 0; kc < 16; ++kc) {
    if (kc == 0) {
      asm volatile("s_waitcnt vmcnt(0) lgkmcnt(0)" ::: "memory");
    } else {
      asm volatile("s_waitcnt vmcnt(16) lgkmcnt(0)" ::: "memory");
    }
    __builtin_amdgcn_s_barrier();
    __builtin_amdgcn_sched_barrier(0);
    if (kc + 1 < 16) {
      stageK(kc + 1, Ks[(kc + 1) & 1]);
      stageV(kc + 1, Vs[(kc + 1) & 1]);
    }
    const u16* Kc = Ks[kc & 1];
    const u16* Vc = Vs[kc & 1];

    f32x4 acc[4];
#pragma unroll
    for (int ni = 0; ni < 4; ni++) acc[ni] = zero4();
    __builtin_amdgcn_s_setprio(1);
#pragma unroll
    for (int ni = 0; ni < 4; ++ni) {
      int t = ni * 16 + lr;
      bf16x8 k0 = *(const bf16x8*)&Kc[t * 64 + (((0 + lq) ^ (lr & 7)) << 3)];
      bf16x8 k1 = *(const bf16x8*)&Kc[t * 64 + (((4 + lq) ^ (lr & 7)) << 3)];
      acc[ni] = __builtin_amdgcn_mfma_f32_16x16x32_bf16(qf[0], k0, acc[ni], 0, 0, 0);
      acc[ni] = __builtin_amdgcn_mfma_f32_16x16x32_bf16(qf[1], k1, acc[ni], 0, 0, 0);
    }
    __builtin_amdgcn_s_setprio(0);

#pragma unroll
    for (int ni = 0; ni < 4; ni++) {
#pragma unroll
      for (int r = 0; r < 4; r++) {
        float e = __expf(acc[ni][r] * 0.125f);
        float a = e * s1[r];
        a = (a >= alpha) ? a : 0.0f;
        size_t row = (size_t)bh * 1024 + qw + lq * 4 + r;
        masked_out[row * 1024 + kc * 64 + ni * 16 + lr] = a;
        float p = __expf(a);
        s2[r] += p;
        Ps[w][(lq * 4 + r) * 72 + ni * 16 + lr] = f2bf(p);
      }
    }
    asm volatile("s_waitcnt lgkmcnt(0)" ::: "memory");

    bf16x8 pf[2];
#pragma unroll
    for (int kt = 0; kt < 2; kt++)
      pf[kt] = *(const bf16x8*)&Ps[w][lr * 72 + kt * 32 + lq * 8];
    __builtin_amdgcn_s_setprio(1);
#pragma unroll
    for (int dg = 0; dg < 4; dg++) {
      int d = dg * 16 + lr;
      bf16x8 v0 = *(const bf16x8*)&Vc[d * 64 + (((0 + lq) ^ (lr & 7)) << 3)];
      bf16x8 v1 = *(const bf16x8*)&Vc[d * 64 + (((4 + lq) ^ (lr & 7)) << 3)];
      oacc[dg] = __builtin_amdgcn_mfma_f32_16x16x32_bf16(pf[0], v0, oacc[dg], 0, 0, 0);
      oacc[dg] = __builtin_amdgcn_mfma_f32_16x16x32_bf16(pf[1], v1, oacc[dg], 0, 0, 0);
    }
    __builtin_amdgcn_s_setprio(0);
  }

#pragma unroll
  for (int r = 0; r < 4; r++) {
    float v = s2[r];
    v += __shfl_xor(v, 1); v += __shfl_xor(v, 2);
    v += __shfl_xor(v, 4); v += __shfl_xor(v, 8);
    s2[r] = 1.0f / v;
  }
#pragma unroll
  for (int dg = 0; dg < 4; dg++)
#pragma unroll
    for (int r = 0; r < 4; r++) {
      int q = qw + lq * 4 + r;
      attn_out[(size_t)(b * 1024 + q) * 1024 + h * 64 + dg * 16 + lr] =
          f2bf(oacc[dg][r] * s2[r]);
    }
}

// ---------------------------------------------------------------------------
// LayerNorm over D=1024: y = (A + bf2f(Bv) - mu)*rsqrt(var+eps)*g + beta
// ---------------------------------------------------------------------------
__global__ __launch_bounds__(256) void ln_kernel(
    const float* __restrict__ A, const u16* __restrict__ Bv,
    const float* __restrict__ g, const float* __restrict__ beta,
    float* __restrict__ outF, u16* __restrict__ outB) {
  __shared__ float red[4];
  int row = blockIdx.x, t = threadIdx.x;
  const float* pa = A + (size_t)row * 1024;
  const u16* pb = Bv + (size_t)row * 1024;
  float v[4];
  float s = 0.f;
#pragma unroll
  for (int i = 0; i < 4; i++) {
    int c = t + 256 * i;
    v[i] = pa[c] + bf2f(pb[c]);
    s += v[i];
  }
#pragma unroll
  for (int off = 1; off < 64; off <<= 1) s += __shfl_xor(s, off);
  if ((t & 63) == 0) red[t >> 6] = s;
  __syncthreads();
  s = red[0] + red[1] + red[2] + red[3];
  float mu = s * 0.0009765625f;
  float q = 0.f;
#pragma unroll
  for (int i = 0; i < 4; i++) { float d = v[i] - mu; q += d * d; }
  __syncthreads();
#pragma unroll
  for (int off = 1; off < 64; off <<= 1) q += __shfl_xor(q, off);
  if ((t & 63) == 0) red[t >> 6] = q;
  __syncthreads();
  q = red[0] + red[1] + red[2] + red[3];
  float rs = rsqrtf(q * 0.0009765625f + 1e-5f);
#pragma unroll
  for (int i = 0; i < 4; i++) {
    int c = t + 256 * i;
    float y = (v[i] - mu) * rs * g[c] + beta[c];
    if (outF) outF[(size_t)row * 1024 + c] = y;
    if (outB) outB[(size_t)row * 1024 + c] = f2bf(y);
  }
}

// ---------------------------------------------------------------------------
// Workspace (bytes), aliased by lifetime.
// ---------------------------------------------------------------------------
#define WS_BASEB   0
#define WS_FUSB    16777216
#define WS_W       33554432
#define WS_QKV     48234496
#define WS_ATTNO   98566144
#define WS_X       115343360
#define WS_OB      WS_FUSB
#define WS_XB      WS_BASEB
#define WS_H1      WS_ATTNO
#define WS_FFB     WS_QKV
#define WS_YB      (WS_QKV + 16777216)

extern "C" void kernel_launch(void* const* d_in, const int* in_sizes, int n_in,
                              void* d_out, int out_size, void* d_ws, size_t ws_size,
                              hipStream_t stream) {
  const float* base   = (const float*)d_in[0];
  const float* fusion = (const float*)d_in[1];
  const float* Wq     = (const float*)d_in[2];
  const float* Wk     = (const float*)d_in[3];
  const float* Wv     = (const float*)d_in[4];
  const float* Wo     = (const float*)d_in[5];
  const float* g1     = (const float*)d_in[6];
  const float* b1     = (const float*)d_in[7];
  const float* g2     = (const float*)d_in[8];
  const float* b2     = (const float*)d_in[9];
  const float* fc1w   = (const float*)d_in[10];
  const float* fc1b   = (const float*)d_in[11];
  const float* fc2w   = (const float*)d_in[12];
  const float* fc2b   = (const float*)d_in[13];
  const float* rw     = (const float*)d_in[14];
  const float* rb     = (const float*)d_in[15];
  const float* alphap = (const float*)d_in[16];

  char* ws = (char*)d_ws;
  u16* baseb  = (u16*)(ws + WS_BASEB);
  u16* fusb   = (u16*)(ws + WS_FUSB);
  u16* wall   = (u16*)(ws + WS_W);
  u16* Q2     = (u16*)(ws + WS_QKV);
  u16* attno  = (u16*)(ws + WS_ATTNO);
  u16* obufb  = (u16*)(ws + WS_OB);
  float* x    = (float*)(ws + WS_X);
  u16* xb     = (u16*)(ws + WS_XB);
  u16* h1     = (u16*)(ws + WS_H1);
  u16* ffb    = (u16*)(ws + WS_FFB);
  u16* yb     = (u16*)(ws + WS_YB);

  float* final_out  = (float*)d_out;
  float* masked_out = final_out + 8388608;

  // 1. pack (vec4)
  pack_act<<<dim3(8192, 2), 256, 0, stream>>>(base, fusion, baseb, fusb);
  pack_w<<<dim3(1024, 7), 256, 0, stream>>>(Wq, Wk, Wv, Wo, fc1w, fc2w, rw, wall);

  // 2. QKV merged (z: 0=Q plain, 1=K swizzled, 2=Vt) - 4-wave BK=32 kernel
  gemm_bt<EPI_QKV><<<dim3(8, 64, 3), 256, 0, stream>>>(
      baseb, 1024, wall, 1024, 8192, 1024, 1024, nullptr, Q2, nullptr, fusb);

  // 3. attention (flat grid, XCD-swizzled inside, 8 waves)
  attn_kernel<<<dim3(1024), 512, 0, stream>>>(
      Q2, Q2 + 8388608, Q2 + 16777216, alphap, masked_out, attno);

  dim3 g8(8, 32);   // 256 blocks, 1/CU

  // 4. output proj (bf16 out, 8-phase) + LN1
  gemm8ph<EPI_BF16><<<g8, 512, 0, stream>>>(attno, wall + 3 * 1048576,
                                            1024, nullptr, obufb, nullptr);
  ln_kernel<<<8192, 256, 0, stream>>>(base, obufb, g1, b1, x, xb);

  // 5. FFN + LN2 (8-phase)
  gemm8ph<EPI_SILU_BF16><<<g8, 512, 0, stream>>>(xb, wall + 4 * 1048576,
                                                 1024, nullptr, h1, fc1b);
  gemm8ph<EPI_SILU_BF16><<<g8, 512, 0, stream>>>(h1, wall + 5 * 1048576,
                                                 1024, nullptr, ffb, fc2b);
  ln_kernel<<<8192, 256, 0, stream>>>(x, ffb, g2, b2, nullptr, yb);

  // 6. final projection (8-phase)
  gemm8ph<EPI_BIAS_F32><<<g8, 512, 0, stream>>>(yb, wall + 6 * 1048576,
                                                1024, final_out, nullptr, rb);
}

// Round 6
// 916.945 us; speedup vs baseline: 1.0336x; 1.0336x over previous
//
#include <hip/hip_runtime.h>

// ============================================================================
// CrossAttention fused pipeline, MI355X gfx950.  Round 11.
// - R11 lever (algebraic sparse-PV): second softmax decomposed EXACTLY as
//     out = (colsum(V) + sum_kept (exp(a)-1) V) / (1024 + sum_kept (exp(a)-1))
//   With alpha=0.1 over 1024 keys, kept entries are ~nonexistent: per wave
//   16x64 tile, __any(a>=alpha) gates {Ps roundtrip + V read + 8 PV MFMA}.
//   Common path per kc: 1 GLL(K) + 8 QK MFMA + 16 exp + 16 masked stores.
//   V staging deleted (rare path reads V direct from L2).  Base colsum(V)
//   computed once per block (f32, MORE precise than the old bf16 P-MFMA).
// - R10 8-phase tails REVERTED per pre-commit (947 vs R9 940): back to R9
//   gemm_bt8 BK=64 2-phase (best measured).
// - Kept: QKV 4-wave BK=32, XCD swizzles, counted-vmcnt attn barrier,
//   setprio, vec4 packs.
// ============================================================================

typedef unsigned short u16;
typedef __attribute__((ext_vector_type(8))) short  bf16x8;
typedef __attribute__((ext_vector_type(4))) short  s16x4;
typedef __attribute__((ext_vector_type(4))) float  f32x4;

#define GLL16(gp, lp) __builtin_amdgcn_global_load_lds(                     \
    (__attribute__((address_space(1))) const void*)(gp),                    \
    (__attribute__((address_space(3))) void*)(lp), 16, 0, 0)

__device__ __forceinline__ u16 f2bf(float x) {
  union { float f; unsigned u; } v; v.f = x;
  return (u16)((v.u + 0x7FFF + ((v.u >> 16) & 1)) >> 16);   // RNE
}
__device__ __forceinline__ float bf2f(u16 h) {
  union { unsigned u; float f; } v; v.u = ((unsigned)h) << 16;
  return v.f;
}
__device__ __forceinline__ f32x4 zero4() { f32x4 z = {0.f, 0.f, 0.f, 0.f}; return z; }

// ---------------------------------------------------------------------------
// Packing: activations (base,fusion) and 7 weights, fp32 -> bf16, x4 vector.
// ---------------------------------------------------------------------------
__global__ __launch_bounds__(256) void pack_act(const float* __restrict__ a,
                                                const float* __restrict__ b,
                                                u16* __restrict__ outa,
                                                u16* __restrict__ outb) {
  size_t i = (size_t)blockIdx.x * 256 + threadIdx.x;        // vec4 index
  const f32x4* in = (const f32x4*)(blockIdx.y ? b : a);
  s16x4* out = (s16x4*)(blockIdx.y ? outb : outa);
  f32x4 v = in[i];
  s16x4 o;
  o[0] = (short)f2bf(v[0]); o[1] = (short)f2bf(v[1]);
  o[2] = (short)f2bf(v[2]); o[3] = (short)f2bf(v[3]);
  out[i] = o;
}

__global__ __launch_bounds__(256) void pack_w(
    const float* __restrict__ w0, const float* __restrict__ w1,
    const float* __restrict__ w2, const float* __restrict__ w3,
    const float* __restrict__ w4, const float* __restrict__ w5,
    const float* __restrict__ w6, u16* __restrict__ out) {
  size_t i = (size_t)blockIdx.x * 256 + threadIdx.x;        // vec4 index
  const float* in;
  switch (blockIdx.y) {
    case 0: in = w0; break;  case 1: in = w1; break;
    case 2: in = w2; break;  case 3: in = w3; break;
    case 4: in = w4; break;  case 5: in = w5; break;
    default: in = w6; break;
  }
  f32x4 v = ((const f32x4*)in)[i];
  s16x4 o;
  o[0] = (short)f2bf(v[0]); o[1] = (short)f2bf(v[1]);
  o[2] = (short)f2bf(v[2]); o[3] = (short)f2bf(v[3]);
  ((s16x4*)(out + (size_t)blockIdx.y * 1048576))[i] = o;
}

// ---------------------------------------------------------------------------
// GEMM (4-wave, QKV only): C[M,N] = A[M,K] @ W[N,K]^T, bf16, BK=32, dbuf LDS.
// ---------------------------------------------------------------------------
#define EPI_QKV       0
#define EPI_BF16      1
#define EPI_SILU_BF16 4
#define EPI_BIAS_F32  6

template <int EPI>
__global__ __launch_bounds__(256) void gemm_bt(
    const u16* __restrict__ A, int lda,
    const u16* __restrict__ W, int ldw,
    int M, int N, int K,
    float* __restrict__ outF, u16* __restrict__ outU,
    const float* __restrict__ bias,
    const u16* __restrict__ A2) {
  __shared__ u16 As[2][128 * 32];   // 2 x 8 KB
  __shared__ u16 Bs[2][128 * 32];   // 2 x 8 KB
  int tid = threadIdx.x;
  int l = tid & 63, w = tid >> 6;
  int wr = w >> 1, wc = w & 1, lr = l & 15, lq = l >> 4;

  int fid = blockIdx.y * 8 + blockIdx.x;
  int swz = (fid & 7) * 64 + (fid >> 3);
  int m0 = (swz >> 3) * 128, n0 = (swz & 7) * 128;

  const u16* Ap = A;
  const u16* Wp = W;
  u16* outUp = outU;
  if constexpr (EPI == EPI_QKV) {
    int z = blockIdx.z;
    if (z) Ap = A2;                      // K,V read fusion
    Wp = W + (size_t)z * 1048576;        // wq / wk / wv
    outUp = outU + (size_t)z * 8388608;  // Q2 / K2 / Vt
  }

  f32x4 acc[4][4];
#pragma unroll
  for (int i = 0; i < 4; i++)
#pragma unroll
    for (int j = 0; j < 4; j++) acc[i][j] = zero4();

  auto stage = [&](const u16* src, int ld, int r0, int k0, u16* lds) {
#pragma unroll
    for (int j = 0; j < 2; ++j) {
      int seg = j * 256 + tid;               // 512 segs x 16B
      int row = seg >> 2, sp = seg & 3;
      const u16* g = src + (size_t)(r0 + row) * ld + k0 +
                     ((sp ^ ((row >> 1) & 3)) << 3);
      GLL16(g, lds + seg * 8);               // lane-contiguous LDS dest
    }
  };

  int nk = K >> 5;
  stage(Ap, lda, m0, 0, As[0]);
  stage(Wp, ldw, n0, 0, Bs[0]);
  for (int kt = 0; kt < nk; ++kt) {
    __syncthreads();
    if (kt + 1 < nk) {
      stage(Ap, lda, m0, (kt + 1) << 5, As[(kt + 1) & 1]);
      stage(Wp, ldw, n0, (kt + 1) << 5, Bs[(kt + 1) & 1]);
    }
    const u16* Ab = As[kt & 1];
    const u16* Bb = Bs[kt & 1];
    bf16x8 af[4], bw[4];
    int slot = (lq ^ ((lr >> 1) & 3)) << 3;
#pragma unroll
    for (int mi = 0; mi < 4; mi++)
      af[mi] = *(const bf16x8*)&Ab[(wr * 64 + mi * 16 + lr) * 32 + slot];
#pragma unroll
    for (int ni = 0; ni < 4; ni++)
      bw[ni] = *(const bf16x8*)&Bb[(wc * 64 + ni * 16 + lr) * 32 + slot];
#pragma unroll
    for (int mi = 0; mi < 4; mi++)
#pragma unroll
      for (int ni = 0; ni < 4; ni++)
        acc[mi][ni] = __builtin_amdgcn_mfma_f32_16x16x32_bf16(af[mi], bw[ni],
                                                              acc[mi][ni], 0, 0, 0);
  }

#pragma unroll
  for (int mi = 0; mi < 4; mi++) {
#pragma unroll
    for (int ni = 0; ni < 4; ni++) {
      int col = n0 + wc * 64 + ni * 16 + lr;
#pragma unroll
      for (int r = 0; r < 4; r++) {
        int row = m0 + wr * 64 + mi * 16 + lq * 4 + r;
        float v = acc[mi][ni][r];
        if constexpr (EPI == EPI_QKV) {
          int b = row >> 10, t = row & 1023, h = col >> 6, d = col & 63;
          int z = blockIdx.z;
          if (z == 0) {                       // Q2: [bh][t][64] plain
            outUp[((size_t)(b * 16 + h) * 1024 + t) * 64 + d] = f2bf(v);
          } else if (z == 1) {                // K2: XOR-(t&7) swizzled rows
            size_t base = ((size_t)(b * 16 + h) * 1024 + t) * 64;
            outUp[base + (((d >> 3) ^ (t & 7)) << 3) + (d & 7)] = f2bf(v);
          } else {                            // Vt: [bh][d][t], XOR-(d&7) per 64-chunk
            size_t o = ((size_t)(b * 16 + h) * 64 + d) * 1024 + (t & ~63) +
                       ((((t >> 3) & 7) ^ (d & 7)) << 3) + (t & 7);
            outUp[o] = f2bf(v);
          }
        } else if constexpr (EPI == EPI_BF16) {
          outUp[(size_t)row * N + col] = f2bf(v);
        } else if constexpr (EPI == EPI_SILU_BF16) {
          float z = v + bias[col];
          outUp[(size_t)row * N + col] = f2bf(z / (1.f + __expf(-z)));
        } else {
          outF[(size_t)row * N + col] = v + bias[col];
        }
      }
    }
  }
}

// ---------------------------------------------------------------------------
// GEMM 8-wave BK=64 (tail GEMMs): 128x128 tile, 512 thr, 64KB LDS dbuf.
// (R9-proven best tail config; R10's 8-phase reverted.)
// ---------------------------------------------------------------------------
template <int EPI>
__global__ __launch_bounds__(512) void gemm_bt8(
    const u16* __restrict__ A, int lda,
    const u16* __restrict__ W, int ldw,
    int M, int N, int K,
    float* __restrict__ outF, u16* __restrict__ outU,
    const float* __restrict__ bias) {
  __shared__ u16 As[2][128 * 64];   // 2 x 16 KB
  __shared__ u16 Bs[2][128 * 64];   // 2 x 16 KB
  int tid = threadIdx.x;
  int l = tid & 63, w = tid >> 6;                  // 8 waves
  int wr = w >> 2, wc = w & 3, lr = l & 15, lq = l >> 4;

  int fid = blockIdx.y * 8 + blockIdx.x;
  int swz = (fid & 7) * 64 + (fid >> 3);
  int m0 = (swz >> 3) * 128, n0 = (swz & 7) * 128;

  f32x4 acc[4][2];
#pragma unroll
  for (int i = 0; i < 4; i++)
#pragma unroll
    for (int j = 0; j < 2; j++) acc[i][j] = zero4();

  auto stage = [&](const u16* src, int ld, int r0, int k0, u16* lds) {
#pragma unroll
    for (int j = 0; j < 2; ++j) {
      int seg = j * 512 + tid;             // 1024 segs x 16B = 16 KB
      int row = seg >> 3, sp = seg & 7;
      const u16* g = src + (size_t)(r0 + row) * ld + k0 +
                     ((sp ^ (row & 7)) << 3);
      GLL16(g, lds + seg * 8);
    }
  };

  int nk = K >> 6;                          // 16
  stage(A, lda, m0, 0, As[0]);
  stage(W, ldw, n0, 0, Bs[0]);
  for (int kt = 0; kt < nk; ++kt) {
    __syncthreads();
    if (kt + 1 < nk) {
      stage(A, lda, m0, (kt + 1) << 6, As[(kt + 1) & 1]);
      stage(W, ldw, n0, (kt + 1) << 6, Bs[(kt + 1) & 1]);
    }
    const u16* Ab = As[kt & 1];
    const u16* Bb = Bs[kt & 1];
    bf16x8 af[4][2], bw[2][2];
#pragma unroll
    for (int kk = 0; kk < 2; kk++) {
      int slot = ((kk * 4 + lq) ^ (lr & 7)) << 3;
#pragma unroll
      for (int mi = 0; mi < 4; mi++)
        af[mi][kk] = *(const bf16x8*)&Ab[(wr * 64 + mi * 16 + lr) * 64 + slot];
#pragma unroll
      for (int ni = 0; ni < 2; ni++)
        bw[ni][kk] = *(const bf16x8*)&Bb[(wc * 32 + ni * 16 + lr) * 64 + slot];
    }
#pragma unroll
    for (int kk = 0; kk < 2; kk++)
#pragma unroll
      for (int mi = 0; mi < 4; mi++)
#pragma unroll
        for (int ni = 0; ni < 2; ni++)
          acc[mi][ni] = __builtin_amdgcn_mfma_f32_16x16x32_bf16(
              af[mi][kk], bw[ni][kk], acc[mi][ni], 0, 0, 0);
  }

#pragma unroll
  for (int mi = 0; mi < 4; mi++) {
#pragma unroll
    for (int ni = 0; ni < 2; ni++) {
      int col = n0 + wc * 32 + ni * 16 + lr;
#pragma unroll
      for (int r = 0; r < 4; r++) {
        int row = m0 + wr * 64 + mi * 16 + lq * 4 + r;
        float v = acc[mi][ni][r];
        if constexpr (EPI == EPI_BF16) {
          outU[(size_t)row * N + col] = f2bf(v);
        } else if constexpr (EPI == EPI_SILU_BF16) {
          float z = v + bias[col];
          outU[(size_t)row * N + col] = f2bf(z / (1.f + __expf(-z)));
        } else {
          outF[(size_t)row * N + col] = v + bias[col];
        }
      }
    }
  }
}

// ---------------------------------------------------------------------------
// Attention: pass1 (s1 denominators) + sparse-PV pass2.
// 8 waves x 16 q-rows (512 thr), dbuf K staging only.  Grid (1024),
// XCD swizzle: qi = bid>>7, bh = (bid&7)*16 + ((bid>>3)&15).
// Q2 [bh][t][64] plain; K2 [bh][t][64] XOR-(t&7); Vt [bh][d][1024] XOR-(d&7)
// per 64-chunk (row d content is a permutation -> row-sum is swizzle-blind).
// out = (colsum(V) + sum_kept (exp(a)-1) V) / (1024 + sum_kept (exp(a)-1)).
// LDS: Ks 16K + Ps 18K + vsum 256B = ~34.3 KB.
// ---------------------------------------------------------------------------
__global__ __launch_bounds__(512) void attn_kernel(
    const u16* __restrict__ Q2, const u16* __restrict__ K2,
    const u16* __restrict__ Vt, const float* __restrict__ alphap,
    float* __restrict__ masked_out, u16* __restrict__ attn_out) {
  __shared__ __align__(16) u16 Ks[2][4096];        // 16 KB
  __shared__ __align__(16) u16 Ps[8][16 * 72];     // 18 KB
  __shared__ float vsumf[64];

  int tid = threadIdx.x;
  int l = tid & 63, w = tid >> 6, lr = l & 15, lq = l >> 4;   // w in 0..7

  int bid = blockIdx.x;
  int qi  = bid >> 7;
  int bh  = (bid & 7) * 16 + ((bid >> 3) & 15);
  int h = bh & 15, b = bh >> 4;
  int q0 = qi * 128;

  const u16* Qb = Q2 + (size_t)bh * 65536;
  const u16* Kb = K2 + (size_t)bh * 65536;
  const u16* Vb = Vt + (size_t)bh * 65536;
  float alpha = alphap[0];
  int qw = q0 + w * 16;

  auto stageK = [&](int kc, u16* dst) {
    GLL16(Kb + (size_t)kc * 4096 + tid * 8, dst + tid * 8);
  };

  // ---- V column-sum base (f32), cooperative: 8 lanes per d-row ----
  {
    const u16* vrow = Vb + (size_t)(tid >> 3) * 1024 + (size_t)(tid & 7) * 128;
    float vs = 0.f;
#pragma unroll
    for (int i = 0; i < 16; i++) {
      bf16x8 vv = *(const bf16x8*)&vrow[i * 8];
#pragma unroll
      for (int j = 0; j < 8; j++) vs += bf2f((u16)vv[j]);
    }
    vs += __shfl_xor(vs, 1); vs += __shfl_xor(vs, 2); vs += __shfl_xor(vs, 4);
    if ((tid & 7) == 0) vsumf[tid >> 3] = vs;
  }

  bf16x8 qf[2];
#pragma unroll
  for (int kt = 0; kt < 2; kt++)
    qf[kt] = *(const bf16x8*)(Qb + (size_t)(qw + lr) * 64 + kt * 32 + lq * 8);

  float s1[4] = {0.f, 0.f, 0.f, 0.f};

  // ---- pass 1: s1 denominators ----
  stageK(0, Ks[0]);
  for (int kc = 0; kc < 16; ++kc) {
    __syncthreads();
    if (kc + 1 < 16) stageK(kc + 1, Ks[(kc + 1) & 1]);
    const u16* Kc = Ks[kc & 1];
    f32x4 acc[4];
#pragma unroll
    for (int ni = 0; ni < 4; ni++) acc[ni] = zero4();
    __builtin_amdgcn_s_setprio(1);
#pragma unroll
    for (int ni = 0; ni < 4; ++ni) {
      int t = ni * 16 + lr;
      bf16x8 k0 = *(const bf16x8*)&Kc[t * 64 + (((0 + lq) ^ (lr & 7)) << 3)];
      bf16x8 k1 = *(const bf16x8*)&Kc[t * 64 + (((4 + lq) ^ (lr & 7)) << 3)];
      acc[ni] = __builtin_amdgcn_mfma_f32_16x16x32_bf16(qf[0], k0, acc[ni], 0, 0, 0);
      acc[ni] = __builtin_amdgcn_mfma_f32_16x16x32_bf16(qf[1], k1, acc[ni], 0, 0, 0);
    }
    __builtin_amdgcn_s_setprio(0);
#pragma unroll
    for (int ni = 0; ni < 4; ni++)
#pragma unroll
      for (int r = 0; r < 4; r++)
        s1[r] += __expf(acc[ni][r] * 0.125f);
  }
#pragma unroll
  for (int r = 0; r < 4; r++) {
    float v = s1[r];
    v += __shfl_xor(v, 1); v += __shfl_xor(v, 2);
    v += __shfl_xor(v, 4); v += __shfl_xor(v, 8);
    s1[r] = 1.0f / v;
  }

  // ---- pass 2: masked write + sparse PV correction ----
  float s2[4] = {0.f, 0.f, 0.f, 0.f};   // correction sums; base 1024 added later
  f32x4 oacc[4];
#pragma unroll
  for (int dg = 0; dg < 4; dg++) oacc[dg] = zero4();

  stageK(0, Ks[0]);
  for (int kc = 0; kc < 16; ++kc) {
    // Counted-vmcnt barrier: per kc, 1 staging load then 16 masked stores.
    // vmcnt(16) completes the load; the 16 newest stores drain lazily.
    if (kc == 0) {
      asm volatile("s_waitcnt vmcnt(0) lgkmcnt(0)" ::: "memory");
    } else {
      asm volatile("s_waitcnt vmcnt(16) lgkmcnt(0)" ::: "memory");
    }
    __builtin_amdgcn_s_barrier();
    __builtin_amdgcn_sched_barrier(0);
    if (kc + 1 < 16) stageK(kc + 1, Ks[(kc + 1) & 1]);
    const u16* Kc = Ks[kc & 1];

    f32x4 acc[4];
#pragma unroll
    for (int ni = 0; ni < 4; ni++) acc[ni] = zero4();
    __builtin_amdgcn_s_setprio(1);
#pragma unroll
    for (int ni = 0; ni < 4; ++ni) {
      int t = ni * 16 + lr;
      bf16x8 k0 = *(const bf16x8*)&Kc[t * 64 + (((0 + lq) ^ (lr & 7)) << 3)];
      bf16x8 k1 = *(const bf16x8*)&Kc[t * 64 + (((4 + lq) ^ (lr & 7)) << 3)];
      acc[ni] = __builtin_amdgcn_mfma_f32_16x16x32_bf16(qf[0], k0, acc[ni], 0, 0, 0);
      acc[ni] = __builtin_amdgcn_mfma_f32_16x16x32_bf16(qf[1], k1, acc[ni], 0, 0, 0);
    }
    __builtin_amdgcn_s_setprio(0);

    float aval[4][4];
    int kept = 0;
#pragma unroll
    for (int ni = 0; ni < 4; ni++) {
#pragma unroll
      for (int r = 0; r < 4; r++) {
        float e = __expf(acc[ni][r] * 0.125f);
        float a = e * s1[r];
        a = (a >= alpha) ? a : 0.0f;
        aval[ni][r] = a;
        kept |= (a != 0.0f);
        size_t row = (size_t)bh * 1024 + qw + lq * 4 + r;
        masked_out[row * 1024 + kc * 64 + ni * 16 + lr] = a;
      }
    }

    // Rare correction path (wave-uniform; no barriers inside).
    if (__any(kept)) {
#pragma unroll
      for (int ni = 0; ni < 4; ni++) {
#pragma unroll
        for (int r = 0; r < 4; r++) {
          float a = aval[ni][r];
          float pm1 = (a != 0.0f) ? (__expf(a) - 1.0f) : 0.0f;
          s2[r] += pm1;
          Ps[w][(lq * 4 + r) * 72 + ni * 16 + lr] = f2bf(pm1);
        }
      }
      asm volatile("s_waitcnt lgkmcnt(0)" ::: "memory");
      bf16x8 pf[2];
#pragma unroll
      for (int kt = 0; kt < 2; kt++)
        pf[kt] = *(const bf16x8*)&Ps[w][lr * 72 + kt * 32 + lq * 8];
      __builtin_amdgcn_s_setprio(1);
#pragma unroll
      for (int dg = 0; dg < 4; dg++) {
        int d = dg * 16 + lr;
        // V read direct from L2 (Vt layout == old LDS tile layout per kc)
        bf16x8 v0 = *(const bf16x8*)&Vb[(size_t)d * 1024 + kc * 64 +
                                        (((0 + lq) ^ (d & 7)) << 3)];
        bf16x8 v1 = *(const bf16x8*)&Vb[(size_t)d * 1024 + kc * 64 +
                                        (((4 + lq) ^ (d & 7)) << 3)];
        oacc[dg] = __builtin_amdgcn_mfma_f32_16x16x32_bf16(pf[0], v0, oacc[dg], 0, 0, 0);
        oacc[dg] = __builtin_amdgcn_mfma_f32_16x16x32_bf16(pf[1], v1, oacc[dg], 0, 0, 0);
      }
      __builtin_amdgcn_s_setprio(0);
    }
  }

  // s2 = 1024 + correction-sum (reduce over the 16 lr lanes)
#pragma unroll
  for (int r = 0; r < 4; r++) {
    float v = s2[r];
    v += __shfl_xor(v, 1); v += __shfl_xor(v, 2);
    v += __shfl_xor(v, 4); v += __shfl_xor(v, 8);
    s2[r] = 1.0f / (1024.0f + v);
  }
#pragma unroll
  for (int dg = 0; dg < 4; dg++)
#pragma unroll
    for (int r = 0; r < 4; r++) {
      int q = qw + lq * 4 + r;
      attn_out[(size_t)(b * 1024 + q) * 1024 + h * 64 + dg * 16 + lr] =
          f2bf((vsumf[dg * 16 + lr] + oacc[dg][r]) * s2[r]);
    }
}

// ---------------------------------------------------------------------------
// LayerNorm over D=1024: y = (A + bf2f(Bv) - mu)*rsqrt(var+eps)*g + beta
// ---------------------------------------------------------------------------
__global__ __launch_bounds__(256) void ln_kernel(
    const float* __restrict__ A, const u16* __restrict__ Bv,
    const float* __restrict__ g, const float* __restrict__ beta,
    float* __restrict__ outF, u16* __restrict__ outB) {
  __shared__ float red[4];
  int row = blockIdx.x, t = threadIdx.x;
  const float* pa = A + (size_t)row * 1024;
  const u16* pb = Bv + (size_t)row * 1024;
  float v[4];
  float s = 0.f;
#pragma unroll
  for (int i = 0; i < 4; i++) {
    int c = t + 256 * i;
    v[i] = pa[c] + bf2f(pb[c]);
    s += v[i];
  }
#pragma unroll
  for (int off = 1; off < 64; off <<= 1) s += __shfl_xor(s, off);
  if ((t & 63) == 0) red[t >> 6] = s;
  __syncthreads();
  s = red[0] + red[1] + red[2] + red[3];
  float mu = s * 0.0009765625f;
  float q = 0.f;
#pragma unroll
  for (int i = 0; i < 4; i++) { float d = v[i] - mu; q += d * d; }
  __syncthreads();
#pragma unroll
  for (int off = 1; off < 64; off <<= 1) q += __shfl_xor(q, off);
  if ((t & 63) == 0) red[t >> 6] = q;
  __syncthreads();
  q = red[0] + red[1] + red[2] + red[3];
  float rs = rsqrtf(q * 0.0009765625f + 1e-5f);
#pragma unroll
  for (int i = 0; i < 4; i++) {
    int c = t + 256 * i;
    float y = (v[i] - mu) * rs * g[c] + beta[c];
    if (outF) outF[(size_t)row * 1024 + c] = y;
    if (outB) outB[(size_t)row * 1024 + c] = f2bf(y);
  }
}

// ---------------------------------------------------------------------------
// Workspace (bytes), aliased by lifetime.
// ---------------------------------------------------------------------------
#define WS_BASEB   0
#define WS_FUSB    16777216
#define WS_W       33554432
#define WS_QKV     48234496
#define WS_ATTNO   98566144
#define WS_X       115343360
#define WS_OB      WS_FUSB
#define WS_XB      WS_BASEB
#define WS_H1      WS_ATTNO
#define WS_FFB     WS_QKV
#define WS_YB      (WS_QKV + 16777216)

extern "C" void kernel_launch(void* const* d_in, const int* in_sizes, int n_in,
                              void* d_out, int out_size, void* d_ws, size_t ws_size,
                              hipStream_t stream) {
  const float* base   = (const float*)d_in[0];
  const float* fusion = (const float*)d_in[1];
  const float* Wq     = (const float*)d_in[2];
  const float* Wk     = (const float*)d_in[3];
  const float* Wv     = (const float*)d_in[4];
  const float* Wo     = (const float*)d_in[5];
  const float* g1     = (const float*)d_in[6];
  const float* b1     = (const float*)d_in[7];
  const float* g2     = (const float*)d_in[8];
  const float* b2     = (const float*)d_in[9];
  const float* fc1w   = (const float*)d_in[10];
  const float* fc1b   = (const float*)d_in[11];
  const float* fc2w   = (const float*)d_in[12];
  const float* fc2b   = (const float*)d_in[13];
  const float* rw     = (const float*)d_in[14];
  const float* rb     = (const float*)d_in[15];
  const float* alphap = (const float*)d_in[16];

  char* ws = (char*)d_ws;
  u16* baseb  = (u16*)(ws + WS_BASEB);
  u16* fusb   = (u16*)(ws + WS_FUSB);
  u16* wall   = (u16*)(ws + WS_W);
  u16* Q2     = (u16*)(ws + WS_QKV);
  u16* attno  = (u16*)(ws + WS_ATTNO);
  u16* obufb  = (u16*)(ws + WS_OB);
  float* x    = (float*)(ws + WS_X);
  u16* xb     = (u16*)(ws + WS_XB);
  u16* h1     = (u16*)(ws + WS_H1);
  u16* ffb    = (u16*)(ws + WS_FFB);
  u16* yb     = (u16*)(ws + WS_YB);

  float* final_out  = (float*)d_out;
  float* masked_out = final_out + 8388608;

  // 1. pack (vec4)
  pack_act<<<dim3(8192, 2), 256, 0, stream>>>(base, fusion, baseb, fusb);
  pack_w<<<dim3(1024, 7), 256, 0, stream>>>(Wq, Wk, Wv, Wo, fc1w, fc2w, rw, wall);

  // 2. QKV merged (z: 0=Q plain, 1=K swizzled, 2=Vt) - 4-wave BK=32 kernel
  gemm_bt<EPI_QKV><<<dim3(8, 64, 3), 256, 0, stream>>>(
      baseb, 1024, wall, 1024, 8192, 1024, 1024, nullptr, Q2, nullptr, fusb);

  // 3. attention (sparse-PV, 8 waves)
  attn_kernel<<<dim3(1024), 512, 0, stream>>>(
      Q2, Q2 + 8388608, Q2 + 16777216, alphap, masked_out, attno);

  dim3 gg(8, 64);

  // 4. output proj (bf16 out, 8-wave BK=64) + LN1
  gemm_bt8<EPI_BF16><<<gg, 512, 0, stream>>>(attno, 1024, wall + 3 * 1048576, 1024,
                                             8192, 1024, 1024, nullptr, obufb, nullptr);
  ln_kernel<<<8192, 256, 0, stream>>>(base, obufb, g1, b1, x, xb);

  // 5. FFN + LN2 (8-wave BK=64)
  gemm_bt8<EPI_SILU_BF16><<<gg, 512, 0, stream>>>(xb, 1024, wall + 4 * 1048576, 1024,
                                                  8192, 1024, 1024, nullptr, h1, fc1b);
  gemm_bt8<EPI_SILU_BF16><<<gg, 512, 0, stream>>>(h1, 1024, wall + 5 * 1048576, 1024,
                                                  8192, 1024, 1024, nullptr, ffb, fc2b);
  ln_kernel<<<8192, 256, 0, stream>>>(x, ffb, g2, b2, nullptr, yb);

  // 6. final projection (8-wave BK=64)
  gemm_bt8<EPI_BIAS_F32><<<gg, 512, 0, stream>>>(yb, 1024, wall + 6 * 1048576, 1024,
                                                 8192, 1024, 1024, final_out, nullptr, rb);
}

// Round 7
// 907.385 us; speedup vs baseline: 1.0445x; 1.0105x over previous
//
#include <hip/hip_runtime.h>

// ============================================================================
// CrossAttention fused pipeline, MI355X gfx950.  Round 12.
// - R12 single lever: QKV z=2 (Vt) epilogue no longer scatter-stores 2B per
//   lane at 2KB stride (64x line-touch amplification, ~1GB L2 traffic for a
//   16MB payload).  The 128x128 output tile is transposed through the dead
//   As/Bs LDS block (aliased, XOR-swizzled) and written as 16B coalesced
//   stores into the same swizzled Vt layout.  Payload bytes unchanged.
// - Kept: R11 sparse-PV attention (exact algebraic decomposition), R9 tail
//   GEMMs (8-wave BK=64), QKV 4-wave BK=32 loop structure, XCD swizzles,
//   counted-vmcnt attn barrier, setprio, vec4 packs.
// ============================================================================

typedef unsigned short u16;
typedef __attribute__((ext_vector_type(8))) short  bf16x8;
typedef __attribute__((ext_vector_type(4))) short  s16x4;
typedef __attribute__((ext_vector_type(4))) float  f32x4;

#define GLL16(gp, lp) __builtin_amdgcn_global_load_lds(                     \
    (__attribute__((address_space(1))) const void*)(gp),                    \
    (__attribute__((address_space(3))) void*)(lp), 16, 0, 0)

__device__ __forceinline__ u16 f2bf(float x) {
  union { float f; unsigned u; } v; v.f = x;
  return (u16)((v.u + 0x7FFF + ((v.u >> 16) & 1)) >> 16);   // RNE
}
__device__ __forceinline__ float bf2f(u16 h) {
  union { unsigned u; float f; } v; v.u = ((unsigned)h) << 16;
  return v.f;
}
__device__ __forceinline__ f32x4 zero4() { f32x4 z = {0.f, 0.f, 0.f, 0.f}; return z; }

// ---------------------------------------------------------------------------
// Packing: activations (base,fusion) and 7 weights, fp32 -> bf16, x4 vector.
// ---------------------------------------------------------------------------
__global__ __launch_bounds__(256) void pack_act(const float* __restrict__ a,
                                                const float* __restrict__ b,
                                                u16* __restrict__ outa,
                                                u16* __restrict__ outb) {
  size_t i = (size_t)blockIdx.x * 256 + threadIdx.x;        // vec4 index
  const f32x4* in = (const f32x4*)(blockIdx.y ? b : a);
  s16x4* out = (s16x4*)(blockIdx.y ? outb : outa);
  f32x4 v = in[i];
  s16x4 o;
  o[0] = (short)f2bf(v[0]); o[1] = (short)f2bf(v[1]);
  o[2] = (short)f2bf(v[2]); o[3] = (short)f2bf(v[3]);
  out[i] = o;
}

__global__ __launch_bounds__(256) void pack_w(
    const float* __restrict__ w0, const float* __restrict__ w1,
    const float* __restrict__ w2, const float* __restrict__ w3,
    const float* __restrict__ w4, const float* __restrict__ w5,
    const float* __restrict__ w6, u16* __restrict__ out) {
  size_t i = (size_t)blockIdx.x * 256 + threadIdx.x;        // vec4 index
  const float* in;
  switch (blockIdx.y) {
    case 0: in = w0; break;  case 1: in = w1; break;
    case 2: in = w2; break;  case 3: in = w3; break;
    case 4: in = w4; break;  case 5: in = w5; break;
    default: in = w6; break;
  }
  f32x4 v = ((const f32x4*)in)[i];
  s16x4 o;
  o[0] = (short)f2bf(v[0]); o[1] = (short)f2bf(v[1]);
  o[2] = (short)f2bf(v[2]); o[3] = (short)f2bf(v[3]);
  ((s16x4*)(out + (size_t)blockIdx.y * 1048576))[i] = o;
}

// ---------------------------------------------------------------------------
// GEMM (4-wave, QKV only): C[M,N] = A[M,K] @ W[N,K]^T, bf16, BK=32, dbuf LDS.
// smem (32KB) holds As[2][4096] | Bs[2][4096] during the k-loop; for z=2 the
// whole block is re-used post-loop as a 128x128 u16 transpose buffer.
// ---------------------------------------------------------------------------
#define EPI_QKV       0
#define EPI_BF16      1
#define EPI_SILU_BF16 4
#define EPI_BIAS_F32  6

template <int EPI>
__global__ __launch_bounds__(256) void gemm_bt(
    const u16* __restrict__ A, int lda,
    const u16* __restrict__ W, int ldw,
    int M, int N, int K,
    float* __restrict__ outF, u16* __restrict__ outU,
    const float* __restrict__ bias,
    const u16* __restrict__ A2) {
  __shared__ __align__(16) u16 smem[16384];   // 32 KB: As[2][4096] | Bs[2][4096]
  int tid = threadIdx.x;
  int l = tid & 63, w = tid >> 6;
  int wr = w >> 1, wc = w & 1, lr = l & 15, lq = l >> 4;

  int fid = blockIdx.y * 8 + blockIdx.x;
  int swz = (fid & 7) * 64 + (fid >> 3);
  int m0 = (swz >> 3) * 128, n0 = (swz & 7) * 128;

  const u16* Ap = A;
  const u16* Wp = W;
  u16* outUp = outU;
  if constexpr (EPI == EPI_QKV) {
    int z = blockIdx.z;
    if (z) Ap = A2;                      // K,V read fusion
    Wp = W + (size_t)z * 1048576;        // wq / wk / wv
    outUp = outU + (size_t)z * 8388608;  // Q2 / K2 / Vt
  }

  f32x4 acc[4][4];
#pragma unroll
  for (int i = 0; i < 4; i++)
#pragma unroll
    for (int j = 0; j < 4; j++) acc[i][j] = zero4();

  auto stage = [&](const u16* src, int ld, int r0, int k0, u16* lds) {
#pragma unroll
    for (int j = 0; j < 2; ++j) {
      int seg = j * 256 + tid;               // 512 segs x 16B
      int row = seg >> 2, sp = seg & 3;
      const u16* g = src + (size_t)(r0 + row) * ld + k0 +
                     ((sp ^ ((row >> 1) & 3)) << 3);
      GLL16(g, lds + seg * 8);               // lane-contiguous LDS dest
    }
  };

  int nk = K >> 5;
  stage(Ap, lda, m0, 0, smem);
  stage(Wp, ldw, n0, 0, smem + 8192);
  for (int kt = 0; kt < nk; ++kt) {
    __syncthreads();
    if (kt + 1 < nk) {
      stage(Ap, lda, m0, (kt + 1) << 5, smem + (((kt + 1) & 1) * 4096));
      stage(Wp, ldw, n0, (kt + 1) << 5, smem + 8192 + (((kt + 1) & 1) * 4096));
    }
    const u16* Ab = smem + ((kt & 1) * 4096);
    const u16* Bb = smem + 8192 + ((kt & 1) * 4096);
    bf16x8 af[4], bw[4];
    int slot = (lq ^ ((lr >> 1) & 3)) << 3;
#pragma unroll
    for (int mi = 0; mi < 4; mi++)
      af[mi] = *(const bf16x8*)&Ab[(wr * 64 + mi * 16 + lr) * 32 + slot];
#pragma unroll
    for (int ni = 0; ni < 4; ni++)
      bw[ni] = *(const bf16x8*)&Bb[(wc * 64 + ni * 16 + lr) * 32 + slot];
#pragma unroll
    for (int mi = 0; mi < 4; mi++)
#pragma unroll
      for (int ni = 0; ni < 4; ni++)
        acc[mi][ni] = __builtin_amdgcn_mfma_f32_16x16x32_bf16(af[mi], bw[ni],
                                                              acc[mi][ni], 0, 0, 0);
  }

  if constexpr (EPI == EPI_QKV) {
    if (blockIdx.z == 2) {
      // ---- R12: Vt epilogue via LDS transpose -> 16B coalesced stores ----
      __syncthreads();                        // all LDS reads of k-loop done
#pragma unroll
      for (int mi = 0; mi < 4; mi++) {
#pragma unroll
        for (int ni = 0; ni < 4; ni++) {
          int c = wc * 64 + ni * 16 + lr;     // local col 0..127
#pragma unroll
          for (int r = 0; r < 4; r++) {
            int rl = wr * 64 + mi * 16 + lq * 4 + r;   // local row 0..127
            smem[c * 128 + (rl ^ ((c & 7) << 3))] = f2bf(acc[mi][ni][r]);
          }
        }
      }
      __syncthreads();
      int c = tid >> 1, half = tid & 1;       // c: 0..127, half: t-chunk
      int hh = (n0 + c) >> 6, d = (n0 + c) & 63;
      int b2 = m0 >> 10, tloc = (m0 & 1023) + half * 64;
      size_t basep = ((size_t)(b2 * 16 + hh) * 64 + d) * 1024 + tloc;
      int x = (c & 7) << 3;
#pragma unroll
      for (int g = 0; g < 8; g++) {
        bf16x8 vv = *(const bf16x8*)&smem[c * 128 + ((half * 64 + g * 8) ^ x)];
        *(bf16x8*)&outUp[basep + ((g ^ (d & 7)) << 3)] = vv;
      }
      return;
    }
  }

#pragma unroll
  for (int mi = 0; mi < 4; mi++) {
#pragma unroll
    for (int ni = 0; ni < 4; ni++) {
      int col = n0 + wc * 64 + ni * 16 + lr;
#pragma unroll
      for (int r = 0; r < 4; r++) {
        int row = m0 + wr * 64 + mi * 16 + lq * 4 + r;
        float v = acc[mi][ni][r];
        if constexpr (EPI == EPI_QKV) {
          int b = row >> 10, t = row & 1023, h = col >> 6, d = col & 63;
          if (blockIdx.z == 0) {              // Q2: [bh][t][64] plain
            outUp[((size_t)(b * 16 + h) * 1024 + t) * 64 + d] = f2bf(v);
          } else {                            // K2: XOR-(t&7) swizzled rows
            size_t base = ((size_t)(b * 16 + h) * 1024 + t) * 64;
            outUp[base + (((d >> 3) ^ (t & 7)) << 3) + (d & 7)] = f2bf(v);
          }
        } else if constexpr (EPI == EPI_BF16) {
          outUp[(size_t)row * N + col] = f2bf(v);
        } else if constexpr (EPI == EPI_SILU_BF16) {
          float z = v + bias[col];
          outUp[(size_t)row * N + col] = f2bf(z / (1.f + __expf(-z)));
        } else {
          outF[(size_t)row * N + col] = v + bias[col];
        }
      }
    }
  }
}

// ---------------------------------------------------------------------------
// GEMM 8-wave BK=64 (tail GEMMs): 128x128 tile, 512 thr, 64KB LDS dbuf.
// ---------------------------------------------------------------------------
template <int EPI>
__global__ __launch_bounds__(512) void gemm_bt8(
    const u16* __restrict__ A, int lda,
    const u16* __restrict__ W, int ldw,
    int M, int N, int K,
    float* __restrict__ outF, u16* __restrict__ outU,
    const float* __restrict__ bias) {
  __shared__ u16 As[2][128 * 64];   // 2 x 16 KB
  __shared__ u16 Bs[2][128 * 64];   // 2 x 16 KB
  int tid = threadIdx.x;
  int l = tid & 63, w = tid >> 6;                  // 8 waves
  int wr = w >> 2, wc = w & 3, lr = l & 15, lq = l >> 4;

  int fid = blockIdx.y * 8 + blockIdx.x;
  int swz = (fid & 7) * 64 + (fid >> 3);
  int m0 = (swz >> 3) * 128, n0 = (swz & 7) * 128;

  f32x4 acc[4][2];
#pragma unroll
  for (int i = 0; i < 4; i++)
#pragma unroll
    for (int j = 0; j < 2; j++) acc[i][j] = zero4();

  auto stage = [&](const u16* src, int ld, int r0, int k0, u16* lds) {
#pragma unroll
    for (int j = 0; j < 2; ++j) {
      int seg = j * 512 + tid;             // 1024 segs x 16B = 16 KB
      int row = seg >> 3, sp = seg & 7;
      const u16* g = src + (size_t)(r0 + row) * ld + k0 +
                     ((sp ^ (row & 7)) << 3);
      GLL16(g, lds + seg * 8);
    }
  };

  int nk = K >> 6;                          // 16
  stage(A, lda, m0, 0, As[0]);
  stage(W, ldw, n0, 0, Bs[0]);
  for (int kt = 0; kt < nk; ++kt) {
    __syncthreads();
    if (kt + 1 < nk) {
      stage(A, lda, m0, (kt + 1) << 6, As[(kt + 1) & 1]);
      stage(W, ldw, n0, (kt + 1) << 6, Bs[(kt + 1) & 1]);
    }
    const u16* Ab = As[kt & 1];
    const u16* Bb = Bs[kt & 1];
    bf16x8 af[4][2], bw[2][2];
#pragma unroll
    for (int kk = 0; kk < 2; kk++) {
      int slot = ((kk * 4 + lq) ^ (lr & 7)) << 3;
#pragma unroll
      for (int mi = 0; mi < 4; mi++)
        af[mi][kk] = *(const bf16x8*)&Ab[(wr * 64 + mi * 16 + lr) * 64 + slot];
#pragma unroll
      for (int ni = 0; ni < 2; ni++)
        bw[ni][kk] = *(const bf16x8*)&Bb[(wc * 32 + ni * 16 + lr) * 64 + slot];
    }
#pragma unroll
    for (int kk = 0; kk < 2; kk++)
#pragma unroll
      for (int mi = 0; mi < 4; mi++)
#pragma unroll
        for (int ni = 0; ni < 2; ni++)
          acc[mi][ni] = __builtin_amdgcn_mfma_f32_16x16x32_bf16(
              af[mi][kk], bw[ni][kk], acc[mi][ni], 0, 0, 0);
  }

#pragma unroll
  for (int mi = 0; mi < 4; mi++) {
#pragma unroll
    for (int ni = 0; ni < 2; ni++) {
      int col = n0 + wc * 32 + ni * 16 + lr;
#pragma unroll
      for (int r = 0; r < 4; r++) {
        int row = m0 + wr * 64 + mi * 16 + lq * 4 + r;
        float v = acc[mi][ni][r];
        if constexpr (EPI == EPI_BF16) {
          outU[(size_t)row * N + col] = f2bf(v);
        } else if constexpr (EPI == EPI_SILU_BF16) {
          float z = v + bias[col];
          outU[(size_t)row * N + col] = f2bf(z / (1.f + __expf(-z)));
        } else {
          outF[(size_t)row * N + col] = v + bias[col];
        }
      }
    }
  }
}

// ---------------------------------------------------------------------------
// Attention: pass1 (s1 denominators) + sparse-PV pass2 (R11).
// 8 waves x 16 q-rows (512 thr), dbuf K staging only.  Grid (1024).
// out = (colsum(V) + sum_kept (exp(a)-1) V) / (1024 + sum_kept (exp(a)-1)).
// ---------------------------------------------------------------------------
__global__ __launch_bounds__(512) void attn_kernel(
    const u16* __restrict__ Q2, const u16* __restrict__ K2,
    const u16* __restrict__ Vt, const float* __restrict__ alphap,
    float* __restrict__ masked_out, u16* __restrict__ attn_out) {
  __shared__ __align__(16) u16 Ks[2][4096];        // 16 KB
  __shared__ __align__(16) u16 Ps[8][16 * 72];     // 18 KB
  __shared__ float vsumf[64];

  int tid = threadIdx.x;
  int l = tid & 63, w = tid >> 6, lr = l & 15, lq = l >> 4;   // w in 0..7

  int bid = blockIdx.x;
  int qi  = bid >> 7;
  int bh  = (bid & 7) * 16 + ((bid >> 3) & 15);
  int h = bh & 15, b = bh >> 4;
  int q0 = qi * 128;

  const u16* Qb = Q2 + (size_t)bh * 65536;
  const u16* Kb = K2 + (size_t)bh * 65536;
  const u16* Vb = Vt + (size_t)bh * 65536;
  float alpha = alphap[0];
  int qw = q0 + w * 16;

  auto stageK = [&](int kc, u16* dst) {
    GLL16(Kb + (size_t)kc * 4096 + tid * 8, dst + tid * 8);
  };

  // ---- V column-sum base (f32), cooperative: 8 lanes per d-row ----
  {
    const u16* vrow = Vb + (size_t)(tid >> 3) * 1024 + (size_t)(tid & 7) * 128;
    float vs = 0.f;
#pragma unroll
    for (int i = 0; i < 16; i++) {
      bf16x8 vv = *(const bf16x8*)&vrow[i * 8];
#pragma unroll
      for (int j = 0; j < 8; j++) vs += bf2f((u16)vv[j]);
    }
    vs += __shfl_xor(vs, 1); vs += __shfl_xor(vs, 2); vs += __shfl_xor(vs, 4);
    if ((tid & 7) == 0) vsumf[tid >> 3] = vs;
  }

  bf16x8 qf[2];
#pragma unroll
  for (int kt = 0; kt < 2; kt++)
    qf[kt] = *(const bf16x8*)(Qb + (size_t)(qw + lr) * 64 + kt * 32 + lq * 8);

  float s1[4] = {0.f, 0.f, 0.f, 0.f};

  // ---- pass 1: s1 denominators ----
  stageK(0, Ks[0]);
  for (int kc = 0; kc < 16; ++kc) {
    __syncthreads();
    if (kc + 1 < 16) stageK(kc + 1, Ks[(kc + 1) & 1]);
    const u16* Kc = Ks[kc & 1];
    f32x4 acc[4];
#pragma unroll
    for (int ni = 0; ni < 4; ni++) acc[ni] = zero4();
    __builtin_amdgcn_s_setprio(1);
#pragma unroll
    for (int ni = 0; ni < 4; ++ni) {
      int t = ni * 16 + lr;
      bf16x8 k0 = *(const bf16x8*)&Kc[t * 64 + (((0 + lq) ^ (lr & 7)) << 3)];
      bf16x8 k1 = *(const bf16x8*)&Kc[t * 64 + (((4 + lq) ^ (lr & 7)) << 3)];
      acc[ni] = __builtin_amdgcn_mfma_f32_16x16x32_bf16(qf[0], k0, acc[ni], 0, 0, 0);
      acc[ni] = __builtin_amdgcn_mfma_f32_16x16x32_bf16(qf[1], k1, acc[ni], 0, 0, 0);
    }
    __builtin_amdgcn_s_setprio(0);
#pragma unroll
    for (int ni = 0; ni < 4; ni++)
#pragma unroll
      for (int r = 0; r < 4; r++)
        s1[r] += __expf(acc[ni][r] * 0.125f);
  }
#pragma unroll
  for (int r = 0; r < 4; r++) {
    float v = s1[r];
    v += __shfl_xor(v, 1); v += __shfl_xor(v, 2);
    v += __shfl_xor(v, 4); v += __shfl_xor(v, 8);
    s1[r] = 1.0f / v;
  }

  // ---- pass 2: masked write + sparse PV correction ----
  float s2[4] = {0.f, 0.f, 0.f, 0.f};
  f32x4 oacc[4];
#pragma unroll
  for (int dg = 0; dg < 4; dg++) oacc[dg] = zero4();

  stageK(0, Ks[0]);
  for (int kc = 0; kc < 16; ++kc) {
    if (kc == 0) {
      asm volatile("s_waitcnt vmcnt(0) lgkmcnt(0)" ::: "memory");
    } else {
      asm volatile("s_waitcnt vmcnt(16) lgkmcnt(0)" ::: "memory");
    }
    __builtin_amdgcn_s_barrier();
    __builtin_amdgcn_sched_barrier(0);
    if (kc + 1 < 16) stageK(kc + 1, Ks[(kc + 1) & 1]);
    const u16* Kc = Ks[kc & 1];

    f32x4 acc[4];
#pragma unroll
    for (int ni = 0; ni < 4; ni++) acc[ni] = zero4();
    __builtin_amdgcn_s_setprio(1);
#pragma unroll
    for (int ni = 0; ni < 4; ++ni) {
      int t = ni * 16 + lr;
      bf16x8 k0 = *(const bf16x8*)&Kc[t * 64 + (((0 + lq) ^ (lr & 7)) << 3)];
      bf16x8 k1 = *(const bf16x8*)&Kc[t * 64 + (((4 + lq) ^ (lr & 7)) << 3)];
      acc[ni] = __builtin_amdgcn_mfma_f32_16x16x32_bf16(qf[0], k0, acc[ni], 0, 0, 0);
      acc[ni] = __builtin_amdgcn_mfma_f32_16x16x32_bf16(qf[1], k1, acc[ni], 0, 0, 0);
    }
    __builtin_amdgcn_s_setprio(0);

    float aval[4][4];
    int kept = 0;
#pragma unroll
    for (int ni = 0; ni < 4; ni++) {
#pragma unroll
      for (int r = 0; r < 4; r++) {
        float e = __expf(acc[ni][r] * 0.125f);
        float a = e * s1[r];
        a = (a >= alpha) ? a : 0.0f;
        aval[ni][r] = a;
        kept |= (a != 0.0f);
        size_t row = (size_t)bh * 1024 + qw + lq * 4 + r;
        masked_out[row * 1024 + kc * 64 + ni * 16 + lr] = a;
      }
    }

    if (__any(kept)) {
#pragma unroll
      for (int ni = 0; ni < 4; ni++) {
#pragma unroll
        for (int r = 0; r < 4; r++) {
          float a = aval[ni][r];
          float pm1 = (a != 0.0f) ? (__expf(a) - 1.0f) : 0.0f;
          s2[r] += pm1;
          Ps[w][(lq * 4 + r) * 72 + ni * 16 + lr] = f2bf(pm1);
        }
      }
      asm volatile("s_waitcnt lgkmcnt(0)" ::: "memory");
      bf16x8 pf[2];
#pragma unroll
      for (int kt = 0; kt < 2; kt++)
        pf[kt] = *(const bf16x8*)&Ps[w][lr * 72 + kt * 32 + lq * 8];
      __builtin_amdgcn_s_setprio(1);
#pragma unroll
      for (int dg = 0; dg < 4; dg++) {
        int d = dg * 16 + lr;
        bf16x8 v0 = *(const bf16x8*)&Vb[(size_t)d * 1024 + kc * 64 +
                                        (((0 + lq) ^ (d & 7)) << 3)];
        bf16x8 v1 = *(const bf16x8*)&Vb[(size_t)d * 1024 + kc * 64 +
                                        (((4 + lq) ^ (d & 7)) << 3)];
        oacc[dg] = __builtin_amdgcn_mfma_f32_16x16x32_bf16(pf[0], v0, oacc[dg], 0, 0, 0);
        oacc[dg] = __builtin_amdgcn_mfma_f32_16x16x32_bf16(pf[1], v1, oacc[dg], 0, 0, 0);
      }
      __builtin_amdgcn_s_setprio(0);
    }
  }

#pragma unroll
  for (int r = 0; r < 4; r++) {
    float v = s2[r];
    v += __shfl_xor(v, 1); v += __shfl_xor(v, 2);
    v += __shfl_xor(v, 4); v += __shfl_xor(v, 8);
    s2[r] = 1.0f / (1024.0f + v);
  }
#pragma unroll
  for (int dg = 0; dg < 4; dg++)
#pragma unroll
    for (int r = 0; r < 4; r++) {
      int q = qw + lq * 4 + r;
      attn_out[(size_t)(b * 1024 + q) * 1024 + h * 64 + dg * 16 + lr] =
          f2bf((vsumf[dg * 16 + lr] + oacc[dg][r]) * s2[r]);
    }
}

// ---------------------------------------------------------------------------
// LayerNorm over D=1024: y = (A + bf2f(Bv) - mu)*rsqrt(var+eps)*g + beta
// ---------------------------------------------------------------------------
__global__ __launch_bounds__(256) void ln_kernel(
    const float* __restrict__ A, const u16* __restrict__ Bv,
    const float* __restrict__ g, const float* __restrict__ beta,
    float* __restrict__ outF, u16* __restrict__ outB) {
  __shared__ float red[4];
  int row = blockIdx.x, t = threadIdx.x;
  const float* pa = A + (size_t)row * 1024;
  const u16* pb = Bv + (size_t)row * 1024;
  float v[4];
  float s = 0.f;
#pragma unroll
  for (int i = 0; i < 4; i++) {
    int c = t + 256 * i;
    v[i] = pa[c] + bf2f(pb[c]);
    s += v[i];
  }
#pragma unroll
  for (int off = 1; off < 64; off <<= 1) s += __shfl_xor(s, off);
  if ((t & 63) == 0) red[t >> 6] = s;
  __syncthreads();
  s = red[0] + red[1] + red[2] + red[3];
  float mu = s * 0.0009765625f;
  float q = 0.f;
#pragma unroll
  for (int i = 0; i < 4; i++) { float d = v[i] - mu; q += d * d; }
  __syncthreads();
#pragma unroll
  for (int off = 1; off < 64; off <<= 1) q += __shfl_xor(q, off);
  if ((t & 63) == 0) red[t >> 6] = q;
  __syncthreads();
  q = red[0] + red[1] + red[2] + red[3];
  float rs = rsqrtf(q * 0.0009765625f + 1e-5f);
#pragma unroll
  for (int i = 0; i < 4; i++) {
    int c = t + 256 * i;
    float y = (v[i] - mu) * rs * g[c] + beta[c];
    if (outF) outF[(size_t)row * 1024 + c] = y;
    if (outB) outB[(size_t)row * 1024 + c] = f2bf(y);
  }
}

// ---------------------------------------------------------------------------
// Workspace (bytes), aliased by lifetime.
// ---------------------------------------------------------------------------
#define WS_BASEB   0
#define WS_FUSB    16777216
#define WS_W       33554432
#define WS_QKV     48234496
#define WS_ATTNO   98566144
#define WS_X       115343360
#define WS_OB      WS_FUSB
#define WS_XB      WS_BASEB
#define WS_H1      WS_ATTNO
#define WS_FFB     WS_QKV
#define WS_YB      (WS_QKV + 16777216)

extern "C" void kernel_launch(void* const* d_in, const int* in_sizes, int n_in,
                              void* d_out, int out_size, void* d_ws, size_t ws_size,
                              hipStream_t stream) {
  const float* base   = (const float*)d_in[0];
  const float* fusion = (const float*)d_in[1];
  const float* Wq     = (const float*)d_in[2];
  const float* Wk     = (const float*)d_in[3];
  const float* Wv     = (const float*)d_in[4];
  const float* Wo     = (const float*)d_in[5];
  const float* g1     = (const float*)d_in[6];
  const float* b1     = (const float*)d_in[7];
  const float* g2     = (const float*)d_in[8];
  const float* b2     = (const float*)d_in[9];
  const float* fc1w   = (const float*)d_in[10];
  const float* fc1b   = (const float*)d_in[11];
  const float* fc2w   = (const float*)d_in[12];
  const float* fc2b   = (const float*)d_in[13];
  const float* rw     = (const float*)d_in[14];
  const float* rb     = (const float*)d_in[15];
  const float* alphap = (const float*)d_in[16];

  char* ws = (char*)d_ws;
  u16* baseb  = (u16*)(ws + WS_BASEB);
  u16* fusb   = (u16*)(ws + WS_FUSB);
  u16* wall   = (u16*)(ws + WS_W);
  u16* Q2     = (u16*)(ws + WS_QKV);
  u16* attno  = (u16*)(ws + WS_ATTNO);
  u16* obufb  = (u16*)(ws + WS_OB);
  float* x    = (float*)(ws + WS_X);
  u16* xb     = (u16*)(ws + WS_XB);
  u16* h1     = (u16*)(ws + WS_H1);
  u16* ffb    = (u16*)(ws + WS_FFB);
  u16* yb     = (u16*)(ws + WS_YB);

  float* final_out  = (float*)d_out;
  float* masked_out = final_out + 8388608;

  // 1. pack (vec4)
  pack_act<<<dim3(8192, 2), 256, 0, stream>>>(base, fusion, baseb, fusb);
  pack_w<<<dim3(1024, 7), 256, 0, stream>>>(Wq, Wk, Wv, Wo, fc1w, fc2w, rw, wall);

  // 2. QKV merged (z: 0=Q plain, 1=K swizzled, 2=Vt LDS-transposed)
  gemm_bt<EPI_QKV><<<dim3(8, 64, 3), 256, 0, stream>>>(
      baseb, 1024, wall, 1024, 8192, 1024, 1024, nullptr, Q2, nullptr, fusb);

  // 3. attention (sparse-PV, 8 waves)
  attn_kernel<<<dim3(1024), 512, 0, stream>>>(
      Q2, Q2 + 8388608, Q2 + 16777216, alphap, masked_out, attno);

  dim3 gg(8, 64);

  // 4. output proj (bf16 out, 8-wave BK=64) + LN1
  gemm_bt8<EPI_BF16><<<gg, 512, 0, stream>>>(attno, 1024, wall + 3 * 1048576, 1024,
                                             8192, 1024, 1024, nullptr, obufb, nullptr);
  ln_kernel<<<8192, 256, 0, stream>>>(base, obufb, g1, b1, x, xb);

  // 5. FFN + LN2 (8-wave BK=64)
  gemm_bt8<EPI_SILU_BF16><<<gg, 512, 0, stream>>>(xb, 1024, wall + 4 * 1048576, 1024,
                                                  8192, 1024, 1024, nullptr, h1, fc1b);
  gemm_bt8<EPI_SILU_BF16><<<gg, 512, 0, stream>>>(h1, 1024, wall + 5 * 1048576, 1024,
                                                  8192, 1024, 1024, nullptr, ffb, fc2b);
  ln_kernel<<<8192, 256, 0, stream>>>(x, ffb, g2, b2, nullptr, yb);

  // 6. final projection (8-wave BK=64)
  gemm_bt8<EPI_BIAS_F32><<<gg, 512, 0, stream>>>(yb, 1024, wall + 6 * 1048576, 1024,
                                                 8192, 1024, 1024, final_out, nullptr, rb);
}